// Round 14
// baseline (147.216 us; speedup 1.0000x reference)
//
#include <hip/hip_runtime.h>
#include <hip/hip_bf16.h>

#define T_SEQ 4096
#define C_EMB 768
#define HEAD  64

typedef short  short4v __attribute__((ext_vector_type(4)));
typedef short  short8  __attribute__((ext_vector_type(8)));
typedef float  floatx4 __attribute__((ext_vector_type(4)));
typedef unsigned int uint2v __attribute__((ext_vector_type(2)));

static __device__ __forceinline__ short f2bf(float v) {
    __hip_bfloat16 h = __float2bfloat16(v);
    return *reinterpret_cast<short*>(&h);
}

// ---------------------------------------------------------------------------
// Fragment layouts (1 KB per fragment, lane-linear so consumer loads are
// 64 lanes x 16 B CONTIGUOUS):
//   Kf/Qf: fid = t16*2 + kh          (t16 = global_row>>4, kh = h>>5)
//          elem[lane*8+e] = X[row16 = lane&15][h = kh*32 + (lane>>4)*8 + e]
//   Vf:    fid = (s64*4 + hb)*2 + kh2  per batch (b<<18 shorts base)
//          elem[lane*8+e] = V[s = s64*64 + kh2*32 + (lane>>4)*8 + e]
//                             [h = hb*16 + (lane&15)]
// ---------------------------------------------------------------------------

// ---------------------------------------------------------------------------
// Kernel 0: fp32 W[768][64] (x3) -> bf16 Wf in MFMA-FRAGMENT order:
//   Wf[((j*24 + kc)*64 + lane)*8 + e] = bf16(W_g[k][n])
// ---------------------------------------------------------------------------
__global__ void wt_transpose_kernel(const float* __restrict__ Wk,
                                    const float* __restrict__ Wq,
                                    const float* __restrict__ Wv,
                                    short* __restrict__ Wf) {
    const int total = 12 * 24 * 64 * 8;   // 147456
    for (int idx = blockIdx.x * blockDim.x + threadIdx.x; idx < total;
         idx += gridDim.x * blockDim.x) {
        int e    = idx & 7;
        int lane = (idx >> 3) & 63;
        int t    = idx >> 9;          // 0..287 = j*24 + kc
        int kc   = t % 24;
        int j    = t / 24;
        int g    = j >> 2;
        int n    = (j & 3) * 16 + (lane & 15);
        int k    = kc * 32 + ((lane >> 4) & 3) * 8 + e;
        const float* W = (g == 0) ? Wk : (g == 1) ? Wq : Wv;
        Wf[idx] = f2bf(W[k * HEAD + n]);
    }
}

// ---------------------------------------------------------------------------
// Kernel 1: QKV via MFMA (GREEN round-9/10 version, verbatim). 512 blocks x
// 512 thr = 8 waves. Block owns 32 rows x 192 cols. Full 768-wide x panel
// staged to LDS once (48.5 KB), 24-step barrier-free MFMA loop; wave w:
// rows (w&1)*16, j-frags (w>>1)*3..+3. Epilogue scatters to LDS then
// copies out coalesced. K prescaled by 768^-0.5*log2(e).
// ---------------------------------------------------------------------------
__global__ __launch_bounds__(512) void qkv_mfma(
    const float* __restrict__ x, const short* __restrict__ Wf,
    const float* __restrict__ bkp, const float* __restrict__ bqp,
    const float* __restrict__ bvp,
    short* __restrict__ Kf, short* __restrict__ Qf, short* __restrict__ Vf) {
    const float scale2 = 0.052058773f;   // 768^-0.5 * log2(e)
    __shared__ __align__(16) short xs[32][776];   // 48.5 KB

    const int tid  = threadIdx.x;        // 0..511
    const int w    = tid >> 6;           // 0..7 (8 waves)
    const int lane = tid & 63;
    const int ln15 = lane & 15, quad = lane >> 4;
    const int rows0 = blockIdx.x * 32;
    const int rw = (w & 1) * 16;         // wave's row offset in tile
    const int jb = (w >> 1) * 3;         // wave's first j-frag (3 each, 0..11)

    // ---- stage 32 rows x 768 floats -> bf16 LDS (2 batches of 6 strips) ----
#pragma unroll
    for (int grp = 0; grp < 2; ++grp) {
        floatx4 stg[6];
#pragma unroll
        for (int i = 0; i < 6; ++i) {
            int o = (grp * 6 + i) * 2048 + tid * 4;   // linear float idx 32x768
            int r = o / 768, col = o - r * 768;        // 768%4==0: no straddle
            stg[i] = *(const floatx4*)(x + (size_t)(rows0 + r) * C_EMB + col);
        }
#pragma unroll
        for (int i = 0; i < 6; ++i) {
            int o = (grp * 6 + i) * 2048 + tid * 4;
            int r = o / 768, col = o - r * 768;
            unsigned p01, p23;
            asm("v_cvt_pk_bf16_f32 %0, %1, %2" : "=v"(p01) : "v"(stg[i][0]), "v"(stg[i][1]));
            asm("v_cvt_pk_bf16_f32 %0, %1, %2" : "=v"(p23) : "v"(stg[i][2]), "v"(stg[i][3]));
            *(uint2v*)&xs[r][col] = (uint2v){p01, p23};
        }
    }
    __syncthreads();

    const short* wp[3];
#pragma unroll
    for (int j0 = 0; j0 < 3; ++j0)
        wp[j0] = Wf + ((size_t)((jb + j0) * 24) * 64 + lane) * 8;

    floatx4 acc[3];
#pragma unroll
    for (int jj = 0; jj < 3; ++jj) acc[jj] = (floatx4){0.f, 0.f, 0.f, 0.f};

    // ---- 24 K-steps, no barriers ----
#pragma unroll
    for (int kc = 0; kc < 24; ++kc) {
        short8 a = *(const short8*)&xs[rw + ln15][kc * 32 + quad * 8];
        short8 wf[3];
#pragma unroll
        for (int jj = 0; jj < 3; ++jj)
            wf[jj] = *(const short8*)(wp[jj] + kc * 512);
#pragma unroll
        for (int jj = 0; jj < 3; ++jj)
            acc[jj] = __builtin_amdgcn_mfma_f32_16x16x32_bf16(a, wf[jj], acc[jj], 0, 0, 0);
    }
    __syncthreads();   // xs reused by epilogue scatter

    // ---- epilogue: bias/scale -> LDS in frag-linear order ----
    // LDS map (shorts): [0,2048) K frags, [2048,4096) Q frags, [4096,6144) V
    short* lds = &xs[0][0];
#pragma unroll
    for (int jj = 0; jj < 3; ++jj) {
        int j  = jb + jj;
        int g  = j >> 2;
        int nl = (j & 3) * 16 + ln15;        // h in [0,64)
        float bias = (g == 0 ? bkp : g == 1 ? bqp : bvp)[nl];
#pragma unroll
        for (int r = 0; r < 4; ++r) {
            int rloc = rw + quad * 4 + r;    // row within block, 0..31
            float v = acc[jj][r] + bias;
            int off;
            short val;
            if (g == 2) {
                val = f2bf(v);
                off = 4096 + ((nl >> 4) << 9) +
                      ((((rloc >> 3) & 3) << 4) | (nl & 15)) * 8 + (rloc & 7);
            } else {
                val = (g == 0) ? f2bf(v * scale2) : f2bf(v);
                int tr = rloc & 15, kh = nl >> 5;
                int hq = (nl >> 3) & 3, he = nl & 7;
                off = (g << 11) + (((rloc >> 4) * 2 + kh) << 9) +
                      (tr | (hq << 4)) * 8 + he;
            }
            lds[off] = val;
        }
    }
    __syncthreads();

    // ---- coalesced copy-out: 768 x 16B chunks, 512 thr x 2 (tail guarded) ----
    {
        int bb = rows0 >> 12, s = rows0 & 4095;
        size_t vbase = ((size_t)bb << 18) +
                       ((size_t)((s >> 6) * 8 + ((s >> 5) & 1)) << 9);
#pragma unroll
        for (int cc = 0; cc < 2; ++cc) {
            int i = (cc * 512 + tid) * 8;        // short index 0..8184
            if (i < 6144) {
                short8 d = *(const short8*)&lds[i];
                if (i < 2048)
                    *(short8*)(Kf + (size_t)rows0 * 64 + i) = d;
                else if (i < 4096)
                    *(short8*)(Qf + (size_t)rows0 * 64 + (i - 2048)) = d;
                else {
                    int iv = i - 4096;
                    *(short8*)(Vf + vbase + (size_t)(iv >> 9) * 1024 + (iv & 511)) = d;
                }
            }
        }
    }
}

// ---------------------------------------------------------------------------
// Kernel 2: causal attention partial. CHUNK-4 + REGISTER PREFETCH (the
// untested cell of the {chunk, prefetch} matrix; round 9 = chunk8+prefetch
// lost to occupancy, round 10 = chunk4+noprefetch is current best).
// Mechanism: the per-tile lgkmcnt(0)+"memory" fence forbids the compiler
// from hoisting tile st+1's global loads above it -> each tile pays full
// L2/L3 latency serially. tile_step issues next-tile loads at its TOP,
// before the fence; lgkmcnt doesn't wait vmcnt, so those loads stay in
// flight across the fence and hide under exp+PV. 1-wave blocks, grid
// (128,16,4) = 4352 useful waves. Plain-store merge, 16 slices.
// ---------------------------------------------------------------------------
__global__ __launch_bounds__(64) void attn_part(
    const short* __restrict__ Kf, const short* __restrict__ Qf,
    const short* __restrict__ Vf, float* __restrict__ Opart,
    float* __restrict__ lpart) {
    __shared__ __align__(16) short Ps[32][72];   // [t_loc][s_loc] wave-local

    int lane = threadIdx.x & 63;
    int ln15 = lane & 15, quad = lane >> 4;
    int g32 = blockIdx.x, c = blockIdx.y, b = blockIdx.z;
    int dtile = g32 >> 1;                 // diagonal s-tile
    int lo = c * 4;
    if (lo > dtile) return;
    int hi = min(dtile, lo + 3);
    int base = g32 * 32;

    // K B-frags (prescaled), loop-invariant — contiguous 1KB loads
    short8 bk[2][2];
    {
        const short* kfp = Kf + ((size_t)(b * 256 + g32 * 2) * 2) * 512 + lane * 8;
#pragma unroll
        for (int tg = 0; tg < 2; ++tg)
#pragma unroll
            for (int kh = 0; kh < 2; ++kh)
                bk[tg][kh] = *(const short8*)(kfp + (tg * 2 + kh) * 512);
    }

    floatx4 o[2][4];
#pragma unroll
    for (int tg = 0; tg < 2; ++tg)
#pragma unroll
        for (int hb = 0; hb < 4; ++hb) o[tg][hb] = (floatx4){0.f, 0.f, 0.f, 0.f};
    float ls[2] = {0.f, 0.f};

    const short* qfp = Qf + ((size_t)(b * 256 + lo * 4) * 2) * 512 + lane * 8;
    const short* vfp = Vf + ((size_t)b << 18) + (size_t)lo * 8 * 512 + lane * 8;

    short8 aqA[4][2], bvA[4][2], aqB[4][2], bvB[4][2];
    // preload tile lo into A
#pragma unroll
    for (int sb = 0; sb < 4; ++sb)
#pragma unroll
        for (int kh = 0; kh < 2; ++kh)
            aqA[sb][kh] = *(const short8*)(qfp + (sb * 2 + kh) * 512);
#pragma unroll
    for (int hb = 0; hb < 4; ++hb)
#pragma unroll
        for (int kh = 0; kh < 2; ++kh)
            bvA[hb][kh] = *(const short8*)(vfp + (hb * 2 + kh) * 512);

    auto tile_step = [&](short8 (&aq)[4][2], short8 (&bv)[4][2],
                         short8 (&aqn)[4][2], short8 (&bvn)[4][2], int st) {
        // prefetch next tile FIRST — issued BEFORE this tile's fence, so
        // the loads stay in flight across it (lgkmcnt != vmcnt)
        if (st < hi) {
            int ti = st + 1 - lo;
#pragma unroll
            for (int sb = 0; sb < 4; ++sb)
#pragma unroll
                for (int kh = 0; kh < 2; ++kh)
                    aqn[sb][kh] = *(const short8*)(qfp + (size_t)ti * 4096 +
                                                   (sb * 2 + kh) * 512);
#pragma unroll
            for (int hb = 0; hb < 4; ++hb)
#pragma unroll
                for (int kh = 0; kh < 2; ++kh)
                    bvn[hb][kh] = *(const short8*)(vfp + (size_t)ti * 4096 +
                                                   (hb * 2 + kh) * 512);
        }

        // S^T = Q . K^T : D row = s_loc = sb*16+quad*4+r, col = t_loc = ln15
        floatx4 sacc[4][2];
#pragma unroll
        for (int sb = 0; sb < 4; ++sb)
#pragma unroll
            for (int tg = 0; tg < 2; ++tg) {
                floatx4 z = (floatx4){0.f, 0.f, 0.f, 0.f};
                z = __builtin_amdgcn_mfma_f32_16x16x32_bf16(aq[sb][0], bk[tg][0], z, 0, 0, 0);
                z = __builtin_amdgcn_mfma_f32_16x16x32_bf16(aq[sb][1], bk[tg][1], z, 0, 0, 0);
                sacc[sb][tg] = z;
            }

        // p = exp2(z) (bounded; scale folded into K); mask diag; pack P
        bool diag = (st == dtile);
        int s0 = st * 64;
#pragma unroll
        for (int tg = 0; tg < 2; ++tg) {
            int tgl = base + tg * 16 + ln15;
#pragma unroll
            for (int sb = 0; sb < 4; ++sb) {
                float pv4[4];
#pragma unroll
                for (int r = 0; r < 4; ++r) {
                    float p = __builtin_amdgcn_exp2f(sacc[sb][tg][r]);
                    if (diag) {
                        int sg = s0 + sb * 16 + quad * 4 + r;
                        p = (sg > tgl) ? 0.f : p;
                    }
                    pv4[r] = p;
                }
                ls[tg] += (pv4[0] + pv4[1]) + (pv4[2] + pv4[3]);
                unsigned a01, a23;
                asm("v_cvt_pk_bf16_f32 %0, %1, %2" : "=v"(a01) : "v"(pv4[0]), "v"(pv4[1]));
                asm("v_cvt_pk_bf16_f32 %0, %1, %2" : "=v"(a23) : "v"(pv4[2]), "v"(pv4[3]));
                *(uint2v*)&Ps[tg * 16 + ln15][sb * 16 + quad * 4] = (uint2v){a01, a23};
            }
        }
        // cross-lane LDS RAW: fence is mandatory (r2..5/9/10 proven)
        __asm__ volatile("s_waitcnt lgkmcnt(0)" ::: "memory");
        short8 ap[2][2];
#pragma unroll
        for (int tg = 0; tg < 2; ++tg) {
            ap[tg][0] = *(const short8*)&Ps[tg * 16 + ln15][quad * 8];
            ap[tg][1] = *(const short8*)&Ps[tg * 16 + ln15][32 + quad * 8];
        }

        // O += P . V
#pragma unroll
        for (int tg = 0; tg < 2; ++tg)
#pragma unroll
            for (int hb = 0; hb < 4; ++hb) {
                o[tg][hb] = __builtin_amdgcn_mfma_f32_16x16x32_bf16(ap[tg][0], bv[hb][0], o[tg][hb], 0, 0, 0);
                o[tg][hb] = __builtin_amdgcn_mfma_f32_16x16x32_bf16(ap[tg][1], bv[hb][1], o[tg][hb], 0, 0, 0);
            }
    };

#pragma unroll
    for (int it = 0; it < 4; it += 2) {
        if (lo + it > hi) break;
        tile_step(aqA, bvA, aqB, bvB, lo + it);
        if (lo + it + 1 > hi) break;
        tile_step(aqB, bvB, aqA, bvA, lo + it + 1);
    }

    // ---- plain-store merge into private chunk slice (b,c) ----
    float* op = Opart + ((size_t)(b * 16 + c) << 12) * HEAD;
    float* lp = lpart + ((size_t)(b * 16 + c) << 12);

#pragma unroll
    for (int tg = 0; tg < 2; ++tg) {
        float v = ls[tg];
        v += __shfl_xor(v, 16, 64);
        v += __shfl_xor(v, 32, 64);
        if (quad == 0)
            lp[base + tg * 16 + ln15] = v;
    }
#pragma unroll
    for (int tg = 0; tg < 2; ++tg)
#pragma unroll
        for (int r = 0; r < 4; ++r) {
            int t = base + tg * 16 + quad * 4 + r;
#pragma unroll
            for (int hb = 0; hb < 4; ++hb)
                op[(size_t)t * HEAD + hb * 16 + ln15] = o[tg][hb][r];
        }
}

// ---------------------------------------------------------------------------
// Kernel 3: out[b,t,h] = sum_c Opart[b,c,t,h] / sum_c lpart[b,c,t]
// chunk c covers s-tiles [4c,4c+3] (s rows 256c..256c+255); contributes
// iff 4c <= t>>6  <=>  c <= t>>8. Exactly matches which waves wrote.
// ---------------------------------------------------------------------------
__global__ __launch_bounds__(256) void attn_div(
    const float* __restrict__ Opart, const float* __restrict__ lpart,
    float* __restrict__ out) {
    int idx = blockIdx.x * 256 + threadIdx.x;   // 0 .. 1048575
    int h = idx & 63;
    int t = (idx >> 6) & 4095;
    int b = idx >> 18;
    int nch = (t >> 8) + 1;
    float os = 0.f, l = 0.f;
    for (int c = 0; c < nch; ++c) {
        size_t s = (size_t)(b * 16 + c) << 12;
        os += Opart[(s + t) * HEAD + h];
        l  += lpart[s + t];
    }
    out[idx] = os / l;
}

extern "C" void kernel_launch(void* const* d_in, const int* in_sizes, int n_in,
                              void* d_out, int out_size, void* d_ws, size_t ws_size,
                              hipStream_t stream) {
    // Size-based input mapping (order-robust; W's and b's keep internal order)
    const int XSZ = 4 * T_SEQ * C_EMB;   // 12582912
    const int WSZ = C_EMB * HEAD;        // 49152
    const int BSZ = HEAD;                // 64
    const float* x = nullptr;
    const float* W[3] = {nullptr, nullptr, nullptr};
    const float* B[3] = {nullptr, nullptr, nullptr};
    int iw = 0, ib = 0;
    for (int i = 0; i < n_in; ++i) {
        if (in_sizes[i] == XSZ) x = (const float*)d_in[i];
        else if (in_sizes[i] == WSZ && iw < 3) W[iw++] = (const float*)d_in[i];
        else if (in_sizes[i] == BSZ && ib < 3) B[ib++] = (const float*)d_in[i];
    }

    short* ws = (short*)d_ws;
    short* Kf = ws;                               // frag-order K bf16   2 MB
    short* Qf = Kf + (size_t)4 * T_SEQ * HEAD;    // frag-order Q bf16   2 MB
    short* Vf = Qf + (size_t)4 * T_SEQ * HEAD;    // frag-order V bf16   2 MB
    short* Wf = Vf + (size_t)4 * HEAD * T_SEQ;    // frag-order W bf16  288 KB
    float* Opart = (float*)(Wf + (size_t)3 * HEAD * C_EMB); // [4][16][4096][64] 64 MB
    float* lpart = Opart + (size_t)64 * T_SEQ * HEAD;       // [4][16][4096] 1 MB

    wt_transpose_kernel<<<96, 256, 0, stream>>>(W[0], W[1], W[2], Wf);
    qkv_mfma<<<512, 512, 0, stream>>>(x, Wf, B[0], B[1], B[2], Kf, Qf, Vf);
    attn_part<<<dim3(128, 16, 4), 64, 0, stream>>>(Kf, Qf, Vf, Opart, lpart);
    attn_div<<<4096, 256, 0, stream>>>(Opart, lpart, (float*)d_out);
}

// Round 15
// 137.340 us; speedup vs baseline: 1.0719x; 1.0719x over previous
//
#include <hip/hip_runtime.h>
#include <hip/hip_bf16.h>

#define T_SEQ 4096
#define C_EMB 768
#define HEAD  64

typedef short  short4v __attribute__((ext_vector_type(4)));
typedef short  short8  __attribute__((ext_vector_type(8)));
typedef float  floatx4 __attribute__((ext_vector_type(4)));
typedef unsigned int uint2v __attribute__((ext_vector_type(2)));

static __device__ __forceinline__ short f2bf(float v) {
    __hip_bfloat16 h = __float2bfloat16(v);
    return *reinterpret_cast<short*>(&h);
}

// ---------------------------------------------------------------------------
// Fragment layouts (1 KB per fragment, lane-linear so consumer loads are
// 64 lanes x 16 B CONTIGUOUS):
//   Kf/Qf: fid = t16*2 + kh          (t16 = global_row>>4, kh = h>>5)
//          elem[lane*8+e] = X[row16 = lane&15][h = kh*32 + (lane>>4)*8 + e]
//   Vf:    fid = (s64*4 + hb)*2 + kh2  per batch (b<<18 shorts base)
//          elem[lane*8+e] = V[s = s64*64 + kh2*32 + (lane>>4)*8 + e]
//                             [h = hb*16 + (lane&15)]
// ---------------------------------------------------------------------------

// ---------------------------------------------------------------------------
// Kernel 0: fp32 W[768][64] (x3) -> bf16 Wf in MFMA-FRAGMENT order:
//   Wf[((j*24 + kc)*64 + lane)*8 + e] = bf16(W_g[k][n])
// ---------------------------------------------------------------------------
__global__ void wt_transpose_kernel(const float* __restrict__ Wk,
                                    const float* __restrict__ Wq,
                                    const float* __restrict__ Wv,
                                    short* __restrict__ Wf) {
    const int total = 12 * 24 * 64 * 8;   // 147456
    for (int idx = blockIdx.x * blockDim.x + threadIdx.x; idx < total;
         idx += gridDim.x * blockDim.x) {
        int e    = idx & 7;
        int lane = (idx >> 3) & 63;
        int t    = idx >> 9;          // 0..287 = j*24 + kc
        int kc   = t % 24;
        int j    = t / 24;
        int g    = j >> 2;
        int n    = (j & 3) * 16 + (lane & 15);
        int k    = kc * 32 + ((lane >> 4) & 3) * 8 + e;
        const float* W = (g == 0) ? Wk : (g == 1) ? Wq : Wv;
        Wf[idx] = f2bf(W[k * HEAD + n]);
    }
}

// ---------------------------------------------------------------------------
// Kernel 1: QKV via MFMA (GREEN round-9/10 version, verbatim). 512 blocks x
// 512 thr = 8 waves. Block owns 32 rows x 192 cols. Full 768-wide x panel
// staged to LDS once (48.5 KB), 24-step barrier-free MFMA loop; wave w:
// rows (w&1)*16, j-frags (w>>1)*3..+3. Epilogue scatters to LDS then
// copies out coalesced. K prescaled by 768^-0.5*log2(e).
// ---------------------------------------------------------------------------
__global__ __launch_bounds__(512) void qkv_mfma(
    const float* __restrict__ x, const short* __restrict__ Wf,
    const float* __restrict__ bkp, const float* __restrict__ bqp,
    const float* __restrict__ bvp,
    short* __restrict__ Kf, short* __restrict__ Qf, short* __restrict__ Vf) {
    const float scale2 = 0.052058773f;   // 768^-0.5 * log2(e)
    __shared__ __align__(16) short xs[32][776];   // 48.5 KB

    const int tid  = threadIdx.x;        // 0..511
    const int w    = tid >> 6;           // 0..7 (8 waves)
    const int lane = tid & 63;
    const int ln15 = lane & 15, quad = lane >> 4;
    const int rows0 = blockIdx.x * 32;
    const int rw = (w & 1) * 16;         // wave's row offset in tile
    const int jb = (w >> 1) * 3;         // wave's first j-frag (3 each, 0..11)

    // ---- stage 32 rows x 768 floats -> bf16 LDS (2 batches of 6 strips) ----
#pragma unroll
    for (int grp = 0; grp < 2; ++grp) {
        floatx4 stg[6];
#pragma unroll
        for (int i = 0; i < 6; ++i) {
            int o = (grp * 6 + i) * 2048 + tid * 4;   // linear float idx 32x768
            int r = o / 768, col = o - r * 768;        // 768%4==0: no straddle
            stg[i] = *(const floatx4*)(x + (size_t)(rows0 + r) * C_EMB + col);
        }
#pragma unroll
        for (int i = 0; i < 6; ++i) {
            int o = (grp * 6 + i) * 2048 + tid * 4;
            int r = o / 768, col = o - r * 768;
            unsigned p01, p23;
            asm("v_cvt_pk_bf16_f32 %0, %1, %2" : "=v"(p01) : "v"(stg[i][0]), "v"(stg[i][1]));
            asm("v_cvt_pk_bf16_f32 %0, %1, %2" : "=v"(p23) : "v"(stg[i][2]), "v"(stg[i][3]));
            *(uint2v*)&xs[r][col] = (uint2v){p01, p23};
        }
    }
    __syncthreads();

    const short* wp[3];
#pragma unroll
    for (int j0 = 0; j0 < 3; ++j0)
        wp[j0] = Wf + ((size_t)((jb + j0) * 24) * 64 + lane) * 8;

    floatx4 acc[3];
#pragma unroll
    for (int jj = 0; jj < 3; ++jj) acc[jj] = (floatx4){0.f, 0.f, 0.f, 0.f};

    // ---- 24 K-steps, no barriers ----
#pragma unroll
    for (int kc = 0; kc < 24; ++kc) {
        short8 a = *(const short8*)&xs[rw + ln15][kc * 32 + quad * 8];
        short8 wf[3];
#pragma unroll
        for (int jj = 0; jj < 3; ++jj)
            wf[jj] = *(const short8*)(wp[jj] + kc * 512);
#pragma unroll
        for (int jj = 0; jj < 3; ++jj)
            acc[jj] = __builtin_amdgcn_mfma_f32_16x16x32_bf16(a, wf[jj], acc[jj], 0, 0, 0);
    }
    __syncthreads();   // xs reused by epilogue scatter

    // ---- epilogue: bias/scale -> LDS in frag-linear order ----
    // LDS map (shorts): [0,2048) K frags, [2048,4096) Q frags, [4096,6144) V
    short* lds = &xs[0][0];
#pragma unroll
    for (int jj = 0; jj < 3; ++jj) {
        int j  = jb + jj;
        int g  = j >> 2;
        int nl = (j & 3) * 16 + ln15;        // h in [0,64)
        float bias = (g == 0 ? bkp : g == 1 ? bqp : bvp)[nl];
#pragma unroll
        for (int r = 0; r < 4; ++r) {
            int rloc = rw + quad * 4 + r;    // row within block, 0..31
            float v = acc[jj][r] + bias;
            int off;
            short val;
            if (g == 2) {
                val = f2bf(v);
                off = 4096 + ((nl >> 4) << 9) +
                      ((((rloc >> 3) & 3) << 4) | (nl & 15)) * 8 + (rloc & 7);
            } else {
                val = (g == 0) ? f2bf(v * scale2) : f2bf(v);
                int tr = rloc & 15, kh = nl >> 5;
                int hq = (nl >> 3) & 3, he = nl & 7;
                off = (g << 11) + (((rloc >> 4) * 2 + kh) << 9) +
                      (tr | (hq << 4)) * 8 + he;
            }
            lds[off] = val;
        }
    }
    __syncthreads();

    // ---- coalesced copy-out: 768 x 16B chunks, 512 thr x 2 (tail guarded) ----
    {
        int bb = rows0 >> 12, s = rows0 & 4095;
        size_t vbase = ((size_t)bb << 18) +
                       ((size_t)((s >> 6) * 8 + ((s >> 5) & 1)) << 9);
#pragma unroll
        for (int cc = 0; cc < 2; ++cc) {
            int i = (cc * 512 + tid) * 8;        // short index 0..8184
            if (i < 6144) {
                short8 d = *(const short8*)&lds[i];
                if (i < 2048)
                    *(short8*)(Kf + (size_t)rows0 * 64 + i) = d;
                else if (i < 4096)
                    *(short8*)(Qf + (size_t)rows0 * 64 + (i - 2048)) = d;
                else {
                    int iv = i - 4096;
                    *(short8*)(Vf + vbase + (size_t)(iv >> 9) * 1024 + (iv & 511)) = d;
                }
            }
        }
    }
}

// ---------------------------------------------------------------------------
// Kernel 2: causal attention partial. GREEN ROUND-10 CONFIG (best measured:
// total 137.2us): chunk-4, 1-wave blocks, grid (128,16,4) = 4352 useful
// waves, simple body (all 16 Q/V loads upfront, VGPR ~84, 6 waves/SIMD).
// ONE addition vs round-10: s_setprio(1)/(0) around the two MFMA clusters
// (measured +4-7% for independent 1-wave attn blocks; hurts only
// barrier-synced multi-wave kernels, which this isn't). Per-tile: QK ->
// exp/pack P -> LDS, lgkmcnt(0)+"memory" fence (cross-lane LDS RAW),
// read P, PV. Plain-store merge into private per-chunk slice (b*16+c).
// FALSIFIED levers (do not retry): register prefetch dbuf (VGPR 144 ->
// occupancy 8%, r9/r14 regress), 4-wave cooperative L1 sharing (r13
// regress, waves drift -> L1 thrash), chunk-8/16 (r0/r9), atomics (r4).
// ---------------------------------------------------------------------------
__global__ __launch_bounds__(64) void attn_part(
    const short* __restrict__ Kf, const short* __restrict__ Qf,
    const short* __restrict__ Vf, float* __restrict__ Opart,
    float* __restrict__ lpart) {
    __shared__ __align__(16) short Ps[32][72];   // [t_loc][s_loc] wave-local

    int lane = threadIdx.x & 63;
    int ln15 = lane & 15, quad = lane >> 4;
    int g32 = blockIdx.x, c = blockIdx.y, b = blockIdx.z;
    int dtile = g32 >> 1;                 // diagonal s-tile
    int lo = c * 4;
    if (lo > dtile) return;
    int hi = min(dtile, lo + 3);
    int base = g32 * 32;

    // K B-frags (prescaled), loop-invariant — contiguous 1KB loads
    short8 bk[2][2];
    {
        const short* kfp = Kf + ((size_t)(b * 256 + g32 * 2) * 2) * 512 + lane * 8;
#pragma unroll
        for (int tg = 0; tg < 2; ++tg)
#pragma unroll
            for (int kh = 0; kh < 2; ++kh)
                bk[tg][kh] = *(const short8*)(kfp + (tg * 2 + kh) * 512);
    }

    floatx4 o[2][4];
#pragma unroll
    for (int tg = 0; tg < 2; ++tg)
#pragma unroll
        for (int hb = 0; hb < 4; ++hb) o[tg][hb] = (floatx4){0.f, 0.f, 0.f, 0.f};
    float ls[2] = {0.f, 0.f};

    const short* qfp = Qf + ((size_t)(b * 256 + lo * 4) * 2) * 512 + lane * 8;
    const short* vfp = Vf + ((size_t)b << 18) + (size_t)lo * 8 * 512 + lane * 8;

    for (int st = lo; st <= hi; ++st) {
        // ALL loads upfront: 8 Q frags + 8 V frags, each 1KB contiguous
        short8 aq[4][2], bv[4][2];
#pragma unroll
        for (int sb = 0; sb < 4; ++sb)
#pragma unroll
            for (int kh = 0; kh < 2; ++kh)
                aq[sb][kh] = *(const short8*)(qfp + (sb * 2 + kh) * 512);
#pragma unroll
        for (int hb = 0; hb < 4; ++hb)
#pragma unroll
            for (int kh = 0; kh < 2; ++kh)
                bv[hb][kh] = *(const short8*)(vfp + (hb * 2 + kh) * 512);

        // S^T = Q . K^T : D row = s_loc = sb*16+quad*4+r, col = t_loc = ln15
        floatx4 sacc[4][2];
        __builtin_amdgcn_s_setprio(1);
#pragma unroll
        for (int sb = 0; sb < 4; ++sb)
#pragma unroll
            for (int tg = 0; tg < 2; ++tg) {
                floatx4 z = (floatx4){0.f, 0.f, 0.f, 0.f};
                z = __builtin_amdgcn_mfma_f32_16x16x32_bf16(aq[sb][0], bk[tg][0], z, 0, 0, 0);
                z = __builtin_amdgcn_mfma_f32_16x16x32_bf16(aq[sb][1], bk[tg][1], z, 0, 0, 0);
                sacc[sb][tg] = z;
            }
        __builtin_amdgcn_s_setprio(0);

        // p = exp2(z) (bounded; scale folded into K); mask diag; pack P
        bool diag = (st == dtile);
        int s0 = st * 64;
#pragma unroll
        for (int tg = 0; tg < 2; ++tg) {
            int tgl = base + tg * 16 + ln15;
#pragma unroll
            for (int sb = 0; sb < 4; ++sb) {
                float pv4[4];
#pragma unroll
                for (int r = 0; r < 4; ++r) {
                    float p = __builtin_amdgcn_exp2f(sacc[sb][tg][r]);
                    if (diag) {
                        int sg = s0 + sb * 16 + quad * 4 + r;
                        p = (sg > tgl) ? 0.f : p;
                    }
                    pv4[r] = p;
                }
                ls[tg] += (pv4[0] + pv4[1]) + (pv4[2] + pv4[3]);
                unsigned a01, a23;
                asm("v_cvt_pk_bf16_f32 %0, %1, %2" : "=v"(a01) : "v"(pv4[0]), "v"(pv4[1]));
                asm("v_cvt_pk_bf16_f32 %0, %1, %2" : "=v"(a23) : "v"(pv4[2]), "v"(pv4[3]));
                *(uint2v*)&Ps[tg * 16 + ln15][sb * 16 + quad * 4] = (uint2v){a01, a23};
            }
        }
        // cross-lane LDS RAW: fence is mandatory (r2..5/9/10 proven)
        __asm__ volatile("s_waitcnt lgkmcnt(0)" ::: "memory");
        short8 ap[2][2];
#pragma unroll
        for (int tg = 0; tg < 2; ++tg) {
            ap[tg][0] = *(const short8*)&Ps[tg * 16 + ln15][quad * 8];
            ap[tg][1] = *(const short8*)&Ps[tg * 16 + ln15][32 + quad * 8];
        }

        // O += P . V
        __builtin_amdgcn_s_setprio(1);
#pragma unroll
        for (int tg = 0; tg < 2; ++tg)
#pragma unroll
            for (int hb = 0; hb < 4; ++hb) {
                o[tg][hb] = __builtin_amdgcn_mfma_f32_16x16x32_bf16(ap[tg][0], bv[hb][0], o[tg][hb], 0, 0, 0);
                o[tg][hb] = __builtin_amdgcn_mfma_f32_16x16x32_bf16(ap[tg][1], bv[hb][1], o[tg][hb], 0, 0, 0);
            }
        __builtin_amdgcn_s_setprio(0);

        qfp += 8 * 512;
        vfp += 8 * 512;
    }

    // ---- plain-store merge into private chunk slice (b,c) ----
    float* op = Opart + ((size_t)(b * 16 + c) << 12) * HEAD;
    float* lp = lpart + ((size_t)(b * 16 + c) << 12);

#pragma unroll
    for (int tg = 0; tg < 2; ++tg) {
        float v = ls[tg];
        v += __shfl_xor(v, 16, 64);
        v += __shfl_xor(v, 32, 64);
        if (quad == 0)
            lp[base + tg * 16 + ln15] = v;
    }
#pragma unroll
    for (int tg = 0; tg < 2; ++tg)
#pragma unroll
        for (int r = 0; r < 4; ++r) {
            int t = base + tg * 16 + quad * 4 + r;
#pragma unroll
            for (int hb = 0; hb < 4; ++hb)
                op[(size_t)t * HEAD + hb * 16 + ln15] = o[tg][hb][r];
        }
}

// ---------------------------------------------------------------------------
// Kernel 3: out[b,t,h] = sum_c Opart[b,c,t,h] / sum_c lpart[b,c,t]
// chunk c covers s-tiles [4c,4c+3] (s rows 256c..256c+255); contributes
// iff 4c <= t>>6  <=>  c <= t>>8. Exactly matches which waves wrote.
// ---------------------------------------------------------------------------
__global__ __launch_bounds__(256) void attn_div(
    const float* __restrict__ Opart, const float* __restrict__ lpart,
    float* __restrict__ out) {
    int idx = blockIdx.x * 256 + threadIdx.x;   // 0 .. 1048575
    int h = idx & 63;
    int t = (idx >> 6) & 4095;
    int b = idx >> 18;
    int nch = (t >> 8) + 1;
    float os = 0.f, l = 0.f;
    for (int c = 0; c < nch; ++c) {
        size_t s = (size_t)(b * 16 + c) << 12;
        os += Opart[(s + t) * HEAD + h];
        l  += lpart[s + t];
    }
    out[idx] = os / l;
}

extern "C" void kernel_launch(void* const* d_in, const int* in_sizes, int n_in,
                              void* d_out, int out_size, void* d_ws, size_t ws_size,
                              hipStream_t stream) {
    // Size-based input mapping (order-robust; W's and b's keep internal order)
    const int XSZ = 4 * T_SEQ * C_EMB;   // 12582912
    const int WSZ = C_EMB * HEAD;        // 49152
    const int BSZ = HEAD;                // 64
    const float* x = nullptr;
    const float* W[3] = {nullptr, nullptr, nullptr};
    const float* B[3] = {nullptr, nullptr, nullptr};
    int iw = 0, ib = 0;
    for (int i = 0; i < n_in; ++i) {
        if (in_sizes[i] == XSZ) x = (const float*)d_in[i];
        else if (in_sizes[i] == WSZ && iw < 3) W[iw++] = (const float*)d_in[i];
        else if (in_sizes[i] == BSZ && ib < 3) B[ib++] = (const float*)d_in[i];
    }

    short* ws = (short*)d_ws;
    short* Kf = ws;                               // frag-order K bf16   2 MB
    short* Qf = Kf + (size_t)4 * T_SEQ * HEAD;    // frag-order Q bf16   2 MB
    short* Vf = Qf + (size_t)4 * T_SEQ * HEAD;    // frag-order V bf16   2 MB
    short* Wf = Vf + (size_t)4 * HEAD * T_SEQ;    // frag-order W bf16  288 KB
    float* Opart = (float*)(Wf + (size_t)3 * HEAD * C_EMB); // [4][16][4096][64] 64 MB
    float* lpart = Opart + (size_t)64 * T_SEQ * HEAD;       // [4][16][4096] 1 MB

    wt_transpose_kernel<<<96, 256, 0, stream>>>(W[0], W[1], W[2], Wf);
    qkv_mfma<<<512, 512, 0, stream>>>(x, Wf, B[0], B[1], B[2], Kf, Qf, Vf);
    attn_part<<<dim3(128, 16, 4), 64, 0, stream>>>(Kf, Qf, Vf, Opart, lpart);
    attn_div<<<4096, 256, 0, stream>>>(Opart, lpart, (float*)d_out);
}

// Round 16
// 133.962 us; speedup vs baseline: 1.0989x; 1.0252x over previous
//
#include <hip/hip_runtime.h>
#include <hip/hip_bf16.h>

#define T_SEQ 4096
#define C_EMB 768
#define HEAD  64

typedef short  short4v __attribute__((ext_vector_type(4)));
typedef short  short8  __attribute__((ext_vector_type(8)));
typedef float  floatx4 __attribute__((ext_vector_type(4)));
typedef unsigned int uint2v __attribute__((ext_vector_type(2)));

static __device__ __forceinline__ short f2bf(float v) {
    __hip_bfloat16 h = __float2bfloat16(v);
    return *reinterpret_cast<short*>(&h);
}

// ---------------------------------------------------------------------------
// Fragment layouts (1 KB per fragment, lane-linear so consumer loads are
// 64 lanes x 16 B CONTIGUOUS):
//   Kf/Qf: fid = t16*2 + kh          (t16 = global_row>>4, kh = h>>5)
//          elem[lane*8+e] = X[row16 = lane&15][h = kh*32 + (lane>>4)*8 + e]
//   Vf:    fid = (s64*4 + hb)*2 + kh2  per batch (b<<18 shorts base)
//          elem[lane*8+e] = V[s = s64*64 + kh2*32 + (lane>>4)*8 + e]
//                             [h = hb*16 + (lane&15)]
// ---------------------------------------------------------------------------

// ---------------------------------------------------------------------------
// Kernel 0: fp32 W[768][64] (x3) -> bf16 Wf in MFMA-FRAGMENT order:
//   Wf[((j*24 + kc)*64 + lane)*8 + e] = bf16(W_g[k][n])
// ---------------------------------------------------------------------------
__global__ void wt_transpose_kernel(const float* __restrict__ Wk,
                                    const float* __restrict__ Wq,
                                    const float* __restrict__ Wv,
                                    short* __restrict__ Wf) {
    const int total = 12 * 24 * 64 * 8;   // 147456
    for (int idx = blockIdx.x * blockDim.x + threadIdx.x; idx < total;
         idx += gridDim.x * blockDim.x) {
        int e    = idx & 7;
        int lane = (idx >> 3) & 63;
        int t    = idx >> 9;          // 0..287 = j*24 + kc
        int kc   = t % 24;
        int j    = t / 24;
        int g    = j >> 2;
        int n    = (j & 3) * 16 + (lane & 15);
        int k    = kc * 32 + ((lane >> 4) & 3) * 8 + e;
        const float* W = (g == 0) ? Wk : (g == 1) ? Wq : Wv;
        Wf[idx] = f2bf(W[k * HEAD + n]);
    }
}

// ---------------------------------------------------------------------------
// Kernel 1: QKV via MFMA (GREEN round-9/10 version, verbatim). 512 blocks x
// 512 thr = 8 waves. Block owns 32 rows x 192 cols. Full 768-wide x panel
// staged to LDS once (48.5 KB), 24-step barrier-free MFMA loop; wave w:
// rows (w&1)*16, j-frags (w>>1)*3..+3. Epilogue scatters to LDS then
// copies out coalesced. K prescaled by 768^-0.5*log2(e).
// ---------------------------------------------------------------------------
__global__ __launch_bounds__(512) void qkv_mfma(
    const float* __restrict__ x, const short* __restrict__ Wf,
    const float* __restrict__ bkp, const float* __restrict__ bqp,
    const float* __restrict__ bvp,
    short* __restrict__ Kf, short* __restrict__ Qf, short* __restrict__ Vf) {
    const float scale2 = 0.052058773f;   // 768^-0.5 * log2(e)
    __shared__ __align__(16) short xs[32][776];   // 48.5 KB

    const int tid  = threadIdx.x;        // 0..511
    const int w    = tid >> 6;           // 0..7 (8 waves)
    const int lane = tid & 63;
    const int ln15 = lane & 15, quad = lane >> 4;
    const int rows0 = blockIdx.x * 32;
    const int rw = (w & 1) * 16;         // wave's row offset in tile
    const int jb = (w >> 1) * 3;         // wave's first j-frag (3 each, 0..11)

    // ---- stage 32 rows x 768 floats -> bf16 LDS (2 batches of 6 strips) ----
#pragma unroll
    for (int grp = 0; grp < 2; ++grp) {
        floatx4 stg[6];
#pragma unroll
        for (int i = 0; i < 6; ++i) {
            int o = (grp * 6 + i) * 2048 + tid * 4;   // linear float idx 32x768
            int r = o / 768, col = o - r * 768;        // 768%4==0: no straddle
            stg[i] = *(const floatx4*)(x + (size_t)(rows0 + r) * C_EMB + col);
        }
#pragma unroll
        for (int i = 0; i < 6; ++i) {
            int o = (grp * 6 + i) * 2048 + tid * 4;
            int r = o / 768, col = o - r * 768;
            unsigned p01, p23;
            asm("v_cvt_pk_bf16_f32 %0, %1, %2" : "=v"(p01) : "v"(stg[i][0]), "v"(stg[i][1]));
            asm("v_cvt_pk_bf16_f32 %0, %1, %2" : "=v"(p23) : "v"(stg[i][2]), "v"(stg[i][3]));
            *(uint2v*)&xs[r][col] = (uint2v){p01, p23};
        }
    }
    __syncthreads();

    const short* wp[3];
#pragma unroll
    for (int j0 = 0; j0 < 3; ++j0)
        wp[j0] = Wf + ((size_t)((jb + j0) * 24) * 64 + lane) * 8;

    floatx4 acc[3];
#pragma unroll
    for (int jj = 0; jj < 3; ++jj) acc[jj] = (floatx4){0.f, 0.f, 0.f, 0.f};

    // ---- 24 K-steps, no barriers ----
#pragma unroll
    for (int kc = 0; kc < 24; ++kc) {
        short8 a = *(const short8*)&xs[rw + ln15][kc * 32 + quad * 8];
        short8 wf[3];
#pragma unroll
        for (int jj = 0; jj < 3; ++jj)
            wf[jj] = *(const short8*)(wp[jj] + kc * 512);
#pragma unroll
        for (int jj = 0; jj < 3; ++jj)
            acc[jj] = __builtin_amdgcn_mfma_f32_16x16x32_bf16(a, wf[jj], acc[jj], 0, 0, 0);
    }
    __syncthreads();   // xs reused by epilogue scatter

    // ---- epilogue: bias/scale -> LDS in frag-linear order ----
    // LDS map (shorts): [0,2048) K frags, [2048,4096) Q frags, [4096,6144) V
    short* lds = &xs[0][0];
#pragma unroll
    for (int jj = 0; jj < 3; ++jj) {
        int j  = jb + jj;
        int g  = j >> 2;
        int nl = (j & 3) * 16 + ln15;        // h in [0,64)
        float bias = (g == 0 ? bkp : g == 1 ? bqp : bvp)[nl];
#pragma unroll
        for (int r = 0; r < 4; ++r) {
            int rloc = rw + quad * 4 + r;    // row within block, 0..31
            float v = acc[jj][r] + bias;
            int off;
            short val;
            if (g == 2) {
                val = f2bf(v);
                off = 4096 + ((nl >> 4) << 9) +
                      ((((rloc >> 3) & 3) << 4) | (nl & 15)) * 8 + (rloc & 7);
            } else {
                val = (g == 0) ? f2bf(v * scale2) : f2bf(v);
                int tr = rloc & 15, kh = nl >> 5;
                int hq = (nl >> 3) & 3, he = nl & 7;
                off = (g << 11) + (((rloc >> 4) * 2 + kh) << 9) +
                      (tr | (hq << 4)) * 8 + he;
            }
            lds[off] = val;
        }
    }
    __syncthreads();

    // ---- coalesced copy-out: 768 x 16B chunks, 512 thr x 2 (tail guarded) ----
    {
        int bb = rows0 >> 12, s = rows0 & 4095;
        size_t vbase = ((size_t)bb << 18) +
                       ((size_t)((s >> 6) * 8 + ((s >> 5) & 1)) << 9);
#pragma unroll
        for (int cc = 0; cc < 2; ++cc) {
            int i = (cc * 512 + tid) * 8;        // short index 0..8184
            if (i < 6144) {
                short8 d = *(const short8*)&lds[i];
                if (i < 2048)
                    *(short8*)(Kf + (size_t)rows0 * 64 + i) = d;
                else if (i < 4096)
                    *(short8*)(Qf + (size_t)rows0 * 64 + (i - 2048)) = d;
                else {
                    int iv = i - 4096;
                    *(short8*)(Vf + vbase + (size_t)(iv >> 9) * 1024 + (iv & 511)) = d;
                }
            }
        }
    }
}

// ---------------------------------------------------------------------------
// Kernel 2: causal attention partial. GREEN ROUND-10/15 CONFIG: chunk-4,
// 1-wave blocks, grid (128,16,4) = 4352 useful waves, simple body (all 16
// Q/V loads upfront, VGPR ~84), setprio around MFMA clusters (neutral but
// harmless, r15). ONE change vs r15: partial O is stored as BF16 (halves
// merge-write bytes 35->18 MB and attn_div's read traffic; partial-O
// magnitudes are small and the final division renormalizes, so bf16
// rounding adds only ~2^-9 relative error). lpart stays fp32.
// FALSIFIED levers (do not retry): register prefetch dbuf (r9/r14),
// 4-wave cooperative (r13), chunk-8/16 (r0/r9), atomics (r4); attn time
// is invariant to wave count (C16@r3 == C4@r10).
// ---------------------------------------------------------------------------
__global__ __launch_bounds__(64) void attn_part(
    const short* __restrict__ Kf, const short* __restrict__ Qf,
    const short* __restrict__ Vf, short* __restrict__ Opart,
    float* __restrict__ lpart) {
    __shared__ __align__(16) short Ps[32][72];   // [t_loc][s_loc] wave-local

    int lane = threadIdx.x & 63;
    int ln15 = lane & 15, quad = lane >> 4;
    int g32 = blockIdx.x, c = blockIdx.y, b = blockIdx.z;
    int dtile = g32 >> 1;                 // diagonal s-tile
    int lo = c * 4;
    if (lo > dtile) return;
    int hi = min(dtile, lo + 3);
    int base = g32 * 32;

    // K B-frags (prescaled), loop-invariant — contiguous 1KB loads
    short8 bk[2][2];
    {
        const short* kfp = Kf + ((size_t)(b * 256 + g32 * 2) * 2) * 512 + lane * 8;
#pragma unroll
        for (int tg = 0; tg < 2; ++tg)
#pragma unroll
            for (int kh = 0; kh < 2; ++kh)
                bk[tg][kh] = *(const short8*)(kfp + (tg * 2 + kh) * 512);
    }

    floatx4 o[2][4];
#pragma unroll
    for (int tg = 0; tg < 2; ++tg)
#pragma unroll
        for (int hb = 0; hb < 4; ++hb) o[tg][hb] = (floatx4){0.f, 0.f, 0.f, 0.f};
    float ls[2] = {0.f, 0.f};

    const short* qfp = Qf + ((size_t)(b * 256 + lo * 4) * 2) * 512 + lane * 8;
    const short* vfp = Vf + ((size_t)b << 18) + (size_t)lo * 8 * 512 + lane * 8;

    for (int st = lo; st <= hi; ++st) {
        // ALL loads upfront: 8 Q frags + 8 V frags, each 1KB contiguous
        short8 aq[4][2], bv[4][2];
#pragma unroll
        for (int sb = 0; sb < 4; ++sb)
#pragma unroll
            for (int kh = 0; kh < 2; ++kh)
                aq[sb][kh] = *(const short8*)(qfp + (sb * 2 + kh) * 512);
#pragma unroll
        for (int hb = 0; hb < 4; ++hb)
#pragma unroll
            for (int kh = 0; kh < 2; ++kh)
                bv[hb][kh] = *(const short8*)(vfp + (hb * 2 + kh) * 512);

        // S^T = Q . K^T : D row = s_loc = sb*16+quad*4+r, col = t_loc = ln15
        floatx4 sacc[4][2];
        __builtin_amdgcn_s_setprio(1);
#pragma unroll
        for (int sb = 0; sb < 4; ++sb)
#pragma unroll
            for (int tg = 0; tg < 2; ++tg) {
                floatx4 z = (floatx4){0.f, 0.f, 0.f, 0.f};
                z = __builtin_amdgcn_mfma_f32_16x16x32_bf16(aq[sb][0], bk[tg][0], z, 0, 0, 0);
                z = __builtin_amdgcn_mfma_f32_16x16x32_bf16(aq[sb][1], bk[tg][1], z, 0, 0, 0);
                sacc[sb][tg] = z;
            }
        __builtin_amdgcn_s_setprio(0);

        // p = exp2(z) (bounded; scale folded into K); mask diag; pack P
        bool diag = (st == dtile);
        int s0 = st * 64;
#pragma unroll
        for (int tg = 0; tg < 2; ++tg) {
            int tgl = base + tg * 16 + ln15;
#pragma unroll
            for (int sb = 0; sb < 4; ++sb) {
                float pv4[4];
#pragma unroll
                for (int r = 0; r < 4; ++r) {
                    float p = __builtin_amdgcn_exp2f(sacc[sb][tg][r]);
                    if (diag) {
                        int sg = s0 + sb * 16 + quad * 4 + r;
                        p = (sg > tgl) ? 0.f : p;
                    }
                    pv4[r] = p;
                }
                ls[tg] += (pv4[0] + pv4[1]) + (pv4[2] + pv4[3]);
                unsigned a01, a23;
                asm("v_cvt_pk_bf16_f32 %0, %1, %2" : "=v"(a01) : "v"(pv4[0]), "v"(pv4[1]));
                asm("v_cvt_pk_bf16_f32 %0, %1, %2" : "=v"(a23) : "v"(pv4[2]), "v"(pv4[3]));
                *(uint2v*)&Ps[tg * 16 + ln15][sb * 16 + quad * 4] = (uint2v){a01, a23};
            }
        }
        // cross-lane LDS RAW: fence is mandatory (r2..5/9/10 proven)
        __asm__ volatile("s_waitcnt lgkmcnt(0)" ::: "memory");
        short8 ap[2][2];
#pragma unroll
        for (int tg = 0; tg < 2; ++tg) {
            ap[tg][0] = *(const short8*)&Ps[tg * 16 + ln15][quad * 8];
            ap[tg][1] = *(const short8*)&Ps[tg * 16 + ln15][32 + quad * 8];
        }

        // O += P . V
        __builtin_amdgcn_s_setprio(1);
#pragma unroll
        for (int tg = 0; tg < 2; ++tg)
#pragma unroll
            for (int hb = 0; hb < 4; ++hb) {
                o[tg][hb] = __builtin_amdgcn_mfma_f32_16x16x32_bf16(ap[tg][0], bv[hb][0], o[tg][hb], 0, 0, 0);
                o[tg][hb] = __builtin_amdgcn_mfma_f32_16x16x32_bf16(ap[tg][1], bv[hb][1], o[tg][hb], 0, 0, 0);
            }
        __builtin_amdgcn_s_setprio(0);

        qfp += 8 * 512;
        vfp += 8 * 512;
    }

    // ---- plain-store merge into private chunk slice (b,c), O as bf16 ----
    short* op = Opart + ((size_t)(b * 16 + c) << 12) * HEAD;
    float* lp = lpart + ((size_t)(b * 16 + c) << 12);

#pragma unroll
    for (int tg = 0; tg < 2; ++tg) {
        float v = ls[tg];
        v += __shfl_xor(v, 16, 64);
        v += __shfl_xor(v, 32, 64);
        if (quad == 0)
            lp[base + tg * 16 + ln15] = v;
    }
#pragma unroll
    for (int tg = 0; tg < 2; ++tg)
#pragma unroll
        for (int r = 0; r < 4; ++r) {
            int t = base + tg * 16 + quad * 4 + r;
#pragma unroll
            for (int hb = 0; hb < 4; ++hb)
                op[(size_t)t * HEAD + hb * 16 + ln15] = f2bf(o[tg][hb][r]);
        }
}

// ---------------------------------------------------------------------------
// Kernel 3: out[b,t,h] = sum_c Opart_bf16[b,c,t,h] / sum_c lpart[b,c,t]
// chunk c covers s-tiles [4c,4c+3]; contributes iff c <= t>>8.
// Vectorized: each thread handles an (h even, h odd) pair -> one 4-B
// bf16x2 load per slice, one float2 store. bf16 hi half needs no shift.
// ---------------------------------------------------------------------------
__global__ __launch_bounds__(256) void attn_div(
    const short* __restrict__ Opart, const float* __restrict__ lpart,
    float* __restrict__ out) {
    int i2 = blockIdx.x * 256 + threadIdx.x;   // 0 .. 524287 (h-pairs)
    int h2 = i2 & 31;              // pair index: h = 2*h2, 2*h2+1
    int t  = (i2 >> 5) & 4095;
    int b  = i2 >> 17;
    int nch = (t >> 8) + 1;
    float o0 = 0.f, o1 = 0.f, l = 0.f;
    for (int c = 0; c < nch; ++c) {
        size_t s = (size_t)(b * 16 + c) << 12;
        unsigned pv = *(const unsigned*)&Opart[(s + t) * HEAD + h2 * 2];
        unsigned u0 = pv << 16;
        unsigned u1 = pv & 0xffff0000u;
        o0 += *reinterpret_cast<float*>(&u0);
        o1 += *reinterpret_cast<float*>(&u1);
        l  += lpart[s + t];
    }
    float inv = 1.f / l;
    float2 res = make_float2(o0 * inv, o1 * inv);
    *(float2*)&out[((size_t)(b * T_SEQ + t)) * HEAD + h2 * 2] = res;
}

extern "C" void kernel_launch(void* const* d_in, const int* in_sizes, int n_in,
                              void* d_out, int out_size, void* d_ws, size_t ws_size,
                              hipStream_t stream) {
    // Size-based input mapping (order-robust; W's and b's keep internal order)
    const int XSZ = 4 * T_SEQ * C_EMB;   // 12582912
    const int WSZ = C_EMB * HEAD;        // 49152
    const int BSZ = HEAD;                // 64
    const float* x = nullptr;
    const float* W[3] = {nullptr, nullptr, nullptr};
    const float* B[3] = {nullptr, nullptr, nullptr};
    int iw = 0, ib = 0;
    for (int i = 0; i < n_in; ++i) {
        if (in_sizes[i] == XSZ) x = (const float*)d_in[i];
        else if (in_sizes[i] == WSZ && iw < 3) W[iw++] = (const float*)d_in[i];
        else if (in_sizes[i] == BSZ && ib < 3) B[ib++] = (const float*)d_in[i];
    }

    short* ws = (short*)d_ws;
    short* Kf = ws;                               // frag-order K bf16   2 MB
    short* Qf = Kf + (size_t)4 * T_SEQ * HEAD;    // frag-order Q bf16   2 MB
    short* Vf = Qf + (size_t)4 * T_SEQ * HEAD;    // frag-order V bf16   2 MB
    short* Wf = Vf + (size_t)4 * HEAD * T_SEQ;    // frag-order W bf16  288 KB
    short* Opart = Wf + (size_t)3 * HEAD * C_EMB; // [4][16][4096][64] bf16 32 MB
    float* lpart = (float*)(Opart + (size_t)64 * T_SEQ * HEAD); // [4][16][4096] 1 MB

    wt_transpose_kernel<<<96, 256, 0, stream>>>(W[0], W[1], W[2], Wf);
    qkv_mfma<<<512, 512, 0, stream>>>(x, Wf, B[0], B[1], B[2], Kf, Qf, Vf);
    attn_part<<<dim3(128, 16, 4), 64, 0, stream>>>(Kf, Qf, Vf, Opart, lpart);
    attn_div<<<2048, 256, 0, stream>>>(Opart, lpart, (float*)d_out);
}